// Round 4
// baseline (912.986 us; speedup 1.0000x reference)
//
#include <hip/hip_runtime.h>

#define NN 8192
#define DD 256
#define TOPK 32
#define SSTRIP 32   // score kernel: column strips (8 blocks/CU -> full occupancy)
#define SW 256      // cols per strip

typedef __attribute__((ext_vector_type(8))) short short8v;
typedef __attribute__((ext_vector_type(4))) float floatx4;

__device__ __forceinline__ unsigned short f2bf(float f) {
  union { float f; unsigned int u; } x;
  x.f = f;
  unsigned int r = x.u + 0x7FFFu + ((x.u >> 16) & 1u);
  return (unsigned short)(r >> 16);
}
__device__ __forceinline__ unsigned short f2h(float f) {
  _Float16 h = (_Float16)f;
  return __builtin_bit_cast(unsigned short, h);
}
__device__ __forceinline__ float h2f(unsigned short u) {
  return (float)__builtin_bit_cast(_Float16, u);
}
// monotone 16-bit key for fp16: a<b (fp16) <=> key(a)<key(b) (uint16)
__device__ __forceinline__ unsigned int hkey(unsigned int u) {
  return (u & 0x8000u) ? ((~u) & 0xFFFFu) : (u | 0x8000u);
}

// ---------------------------------------------------------------------------
// Kernel 0: bf16 conversions. xb = bf16(x); wqkvb = bf16([Wq;Wk;Wv]);
// wgb = bf16(Wg). One float4 group per thread.
// ---------------------------------------------------------------------------
__global__ __launch_bounds__(256) void conv_kernel(
    const float* __restrict__ x,
    const float* __restrict__ Wq, const float* __restrict__ Wk,
    const float* __restrict__ Wv, const float* __restrict__ Wg,
    unsigned short* __restrict__ xb, unsigned short* __restrict__ wqkvb,
    unsigned short* __restrict__ wgb) {
  int g = blockIdx.x * 256 + threadIdx.x;   // float4 group id
  const float* src;
  unsigned short* dst;
  int e;
  if (g < 524288) {                 // x: 2097152 elems
    e = g * 4; src = x + e; dst = xb + e;
  } else if (g < 524288 + 49152) {  // Wq|Wk|Wv: 3 x 65536
    int e2 = (g - 524288) * 4;
    int which = e2 >> 16;
    int off = e2 & 65535;
    src = ((which == 0) ? Wq : (which == 1) ? Wk : Wv) + off;
    dst = wqkvb + which * 65536 + off;
  } else {                          // Wg: 131072
    int e3 = (g - 524288 - 49152) * 4;
    src = Wg + e3; dst = wgb + e3;
  }
  float4 f4 = *(const float4*)src;
  dst[0] = f2bf(f4.x); dst[1] = f2bf(f4.y);
  dst[2] = f2bf(f4.z); dst[3] = f2bf(f4.w);
}

// ---------------------------------------------------------------------------
// Kernel 1: q,k,v = x @ W.T + b via bf16 MFMA. q scaled by 1/16 (folded for
// scores). grid (6, 64, 4): 32 out-features x 128 rows per block (it-loop
// moved to blockIdx.z for 6 blocks/CU occupancy).
// ---------------------------------------------------------------------------
__global__ __launch_bounds__(256) void qkv_kernel(
    const unsigned short* __restrict__ xb,
    const unsigned short* __restrict__ wqkvb,
    const float* __restrict__ bq, const float* __restrict__ bk,
    const float* __restrict__ bvb,
    unsigned short* __restrict__ qb, unsigned short* __restrict__ kb,
    float* __restrict__ v) {
  int tid = threadIdx.x;
  int w = tid >> 6, lane = tid & 63;
  int quad = lane >> 4, l16 = lane & 15;
  int rb = blockIdx.y * 128;
  int cs = blockIdx.x * 128;   // 0..767 in steps of 128 (never crosses 256-bnd)
  int cb = cs + blockIdx.z * 32;

  short8v afrag[2][8];
#pragma unroll
  for (int rh = 0; rh < 2; rh++)
#pragma unroll
    for (int kbi = 0; kbi < 8; kbi++) {
      int row = rb + w * 32 + rh * 16 + l16;
      afrag[rh][kbi] =
          *(const short8v*)(xb + (size_t)row * 256 + kbi * 32 + quad * 8);
    }

  floatx4 zero4 = {0.0f, 0.0f, 0.0f, 0.0f};
  floatx4 acc[2][2];
  acc[0][0] = zero4; acc[0][1] = zero4; acc[1][0] = zero4; acc[1][1] = zero4;
#pragma unroll
  for (int kbi = 0; kbi < 8; kbi++) {
    short8v b0 = *(const short8v*)(wqkvb + (size_t)(cb + l16) * 256 + kbi * 32 + quad * 8);
    short8v b1 = *(const short8v*)(wqkvb + (size_t)(cb + 16 + l16) * 256 + kbi * 32 + quad * 8);
    acc[0][0] = __builtin_amdgcn_mfma_f32_16x16x32_bf16(afrag[0][kbi], b0, acc[0][0], 0, 0, 0);
    acc[0][1] = __builtin_amdgcn_mfma_f32_16x16x32_bf16(afrag[0][kbi], b1, acc[0][1], 0, 0, 0);
    acc[1][0] = __builtin_amdgcn_mfma_f32_16x16x32_bf16(afrag[1][kbi], b0, acc[1][0], 0, 0, 0);
    acc[1][1] = __builtin_amdgcn_mfma_f32_16x16x32_bf16(afrag[1][kbi], b1, acc[1][1], 0, 0, 0);
  }
#pragma unroll
  for (int rh = 0; rh < 2; rh++)
#pragma unroll
    for (int ch = 0; ch < 2; ch++)
#pragma unroll
      for (int r = 0; r < 4; r++) {
        int row = rb + w * 32 + rh * 16 + quad * 4 + r;
        int col = cb + ch * 16 + l16;           // 0..767
        int which = col >> 8;
        int j = col & 255;
        const float* bias = (which == 0) ? bq : (which == 1) ? bk : bvb;
        float val = acc[rh][ch][r] + bias[j];
        size_t o = (size_t)row * 256 + j;
        if (which == 0)      qb[o] = f2bf(val * 0.0625f);   // fold 1/sqrt(d)... = /16
        else if (which == 1) kb[o] = f2bf(val);
        else                 v[o]  = val;
      }
}

// ---------------------------------------------------------------------------
// Kernel 2: biased scores s = q@k^T (q pre-scaled) + log(clip(causal,1e-6)),
// stored fp16 INSIDE the weights buffer (first 16KB of each 32KB row).
// Stored position within 32-col group: p = l16*2 + ch  (col = ch*16 + l16).
// grid (SSTRIP, 64): 256-col strip x 128 rows. Barrier-free streaming MFMA.
// ---------------------------------------------------------------------------
__global__ __launch_bounds__(256) void score_kernel(
    const unsigned short* __restrict__ qb,
    const unsigned short* __restrict__ kb,
    const float* __restrict__ causal,
    float* __restrict__ weights) {
  int tid = threadIdx.x;
  int w = tid >> 6, lane = tid & 63;
  int quad = lane >> 4, l16 = lane & 15;
  int rb = blockIdx.y * 128;
  int cs = blockIdx.x * SW;

  short8v afrag[2][8];
#pragma unroll
  for (int rh = 0; rh < 2; rh++)
#pragma unroll
    for (int kbi = 0; kbi < 8; kbi++) {
      int row = rb + w * 32 + rh * 16 + l16;
      afrag[rh][kbi] =
          *(const short8v*)(qb + (size_t)row * 256 + kbi * 32 + quad * 8);
    }

  floatx4 zero4 = {0.0f, 0.0f, 0.0f, 0.0f};
  for (int it = 0; it < SW / 32; it++) {
    int cb = cs + it * 32;
    floatx4 acc[2][2];
    acc[0][0] = zero4; acc[0][1] = zero4; acc[1][0] = zero4; acc[1][1] = zero4;
#pragma unroll
    for (int kbi = 0; kbi < 8; kbi++) {
      short8v b0 = *(const short8v*)(kb + (size_t)(cb + l16) * 256 + kbi * 32 + quad * 8);
      short8v b1 = *(const short8v*)(kb + (size_t)(cb + 16 + l16) * 256 + kbi * 32 + quad * 8);
      acc[0][0] = __builtin_amdgcn_mfma_f32_16x16x32_bf16(afrag[0][kbi], b0, acc[0][0], 0, 0, 0);
      acc[0][1] = __builtin_amdgcn_mfma_f32_16x16x32_bf16(afrag[0][kbi], b1, acc[0][1], 0, 0, 0);
      acc[1][0] = __builtin_amdgcn_mfma_f32_16x16x32_bf16(afrag[1][kbi], b0, acc[1][0], 0, 0, 0);
      acc[1][1] = __builtin_amdgcn_mfma_f32_16x16x32_bf16(afrag[1][kbi], b1, acc[1][1], 0, 0, 0);
    }
#pragma unroll
    for (int rh = 0; rh < 2; rh++)
#pragma unroll
      for (int r = 0; r < 4; r++) {
        int grow = rb + w * 32 + rh * 16 + quad * 4 + r;
        float c0 = causal[(size_t)grow * NN + cb + l16];
        float c1 = causal[(size_t)grow * NN + cb + 16 + l16];
        float s0 = acc[rh][0][r] + __logf(fmaxf(c0, 1e-6f));
        float s1 = acc[rh][1][r] + __logf(fmaxf(c1, 1e-6f));
        unsigned int pk = (unsigned int)f2h(s0) | ((unsigned int)f2h(s1) << 16);
        unsigned short* sbrow = (unsigned short*)(weights + (size_t)grow * NN);
        *(unsigned int*)(sbrow + cb + l16 * 2) = pk;
      }
  }
}

// ---------------------------------------------------------------------------
// Kernel 3a: per-row top-32 via register binary-search on fp16 keys + softmax.
// Writes COMPACT selC[row*32+i] / selWt[row*32+i] only (no dense write, no
// gather) -> tiny LDS -> 8 blocks/CU resident to hide the barrier chain.
// One block (256 thr) per row. Thread owns stored positions
// {c*2048 + tid*8 + e : c<4, e<8} (coalesced dwordx4 loads).
// ---------------------------------------------------------------------------
__global__ __launch_bounds__(256) void topk_kernel(
    const float* __restrict__ weights,
    int* __restrict__ selC, float* __restrict__ selWt) {
  __shared__ int part[72];        // binary-search partials (17 x 4)
  __shared__ int part2[8];        // scan partials
  __shared__ int selCol[TOPK];
  __shared__ float selSc[TOPK];

  int tid = threadIdx.x;
  int w = tid >> 6, lane = tid & 63;
  int row = blockIdx.x;
  const unsigned short* sb = (const unsigned short*)(weights + (size_t)row * NN);

  // load 32 fp16 scores (coalesced), build packed monotone keys
  uint4 raw[4];
#pragma unroll
  for (int c = 0; c < 4; c++)
    raw[c] = *(const uint4*)(sb + c * 2048 + tid * 8);
  unsigned int keys[16];
#pragma unroll
  for (int c = 0; c < 4; c++) {
    unsigned int rr[4] = {raw[c].x, raw[c].y, raw[c].z, raw[c].w};
#pragma unroll
    for (int u = 0; u < 4; u++) {
      unsigned int klo = hkey(rr[u] & 0xFFFFu);
      unsigned int khi = hkey(rr[u] >> 16);
      keys[c * 4 + u] = klo | (khi << 16);
    }
  }

  // binary search: smallest t with count(key > t) < TOPK  -> t = 32nd key
  int lo = 0, hi = 65535;
#pragma unroll 1
  for (int it = 0; it < 16; it++) {
    unsigned int mid = (unsigned int)((lo + hi) >> 1);
    int cnt = 0;
#pragma unroll
    for (int u = 0; u < 16; u++) {
      cnt += ((keys[u] & 0xFFFFu) > mid);
      cnt += ((keys[u] >> 16) > mid);
    }
#pragma unroll
    for (int off = 32; off >= 1; off >>= 1) cnt += __shfl_xor(cnt, off, 64);
    if (lane == 0) part[it * 4 + w] = cnt;
    __syncthreads();
    int tot = part[it * 4] + part[it * 4 + 1] + part[it * 4 + 2] + part[it * 4 + 3];
    if (lo < hi) { if (tot < TOPK) hi = (int)mid; else lo = (int)mid + 1; }
  }
  unsigned int K = (unsigned int)lo;

  // nGt = count(key > K)
  {
    int cnt = 0;
#pragma unroll
    for (int u = 0; u < 16; u++) {
      cnt += ((keys[u] & 0xFFFFu) > K);
      cnt += ((keys[u] >> 16) > K);
    }
#pragma unroll
    for (int off = 32; off >= 1; off >>= 1) cnt += __shfl_xor(cnt, off, 64);
    if (lane == 0) part[64 + w] = cnt;
  }
  __syncthreads();
  int nGt = part[64] + part[65] + part[66] + part[67];

  // per-thread counts + shuffle-based prefix scans for deterministic slots
  int cGt = 0, cEq = 0;
#pragma unroll
  for (int u = 0; u < 16; u++) {
    unsigned int a = keys[u] & 0xFFFFu, b = keys[u] >> 16;
    cGt += (a > K) + (b > K);
    cEq += (a == K) + (b == K);
  }
  int sGt = cGt;
#pragma unroll
  for (int off = 1; off < 64; off <<= 1) {
    int t = __shfl_up(sGt, off, 64);
    if (lane >= off) sGt += t;
  }
  if (lane == 63) part2[w] = sGt;
  int sEq = cEq;
#pragma unroll
  for (int off = 1; off < 64; off <<= 1) {
    int t = __shfl_up(sEq, off, 64);
    if (lane >= off) sEq += t;
  }
  if (lane == 63) part2[4 + w] = sEq;
  __syncthreads();
  int offGt = 0, offEq = 0;
  for (int j = 0; j < w; j++) { offGt += part2[j]; offEq += part2[4 + j]; }
  int posG = offGt + sGt - cGt;          // exclusive prefix of cGt
  int posT = nGt + offEq + sEq - cEq;    // tie slots after all strict-greater

  // collect selected entries (fixed order -> deterministic)
#pragma unroll
  for (int c = 0; c < 4; c++) {
    unsigned int rr[4] = {raw[c].x, raw[c].y, raw[c].z, raw[c].w};
#pragma unroll
    for (int e = 0; e < 8; e++) {
      unsigned int u16 = (e & 1) ? (rr[e >> 1] >> 16) : (rr[e >> 1] & 0xFFFFu);
      unsigned int k = hkey(u16);
      if (k > K || (k == K && posT < TOPK)) {
        int p = c * 2048 + tid * 8 + e;            // stored position
        int g = p >> 5, wi = p & 31;
        int col = (g << 5) + ((wi & 1) << 4) + (wi >> 1);  // invert store perm
        int slot = (k > K) ? posG : posT;
        selCol[slot] = col;
        selSc[slot] = h2f((unsigned short)u16);
      }
      if (k > K) posG++;
      else if (k == K) posT++;
    }
  }
  __syncthreads();

  // softmax over the 32 selected (wave-parallel, deterministic), compact out
  if (tid < TOPK) {
    float s = selSc[tid];
    float m = s;
#pragma unroll
    for (int off = 16; off >= 1; off >>= 1) m = fmaxf(m, __shfl_xor(m, off, 64));
    float e = __expf(s - m);
    float Z = e;
#pragma unroll
    for (int off = 16; off >= 1; off >>= 1) Z += __shfl_xor(Z, off, 64);
    selC[(size_t)row * TOPK + tid] = selCol[tid];
    selWt[(size_t)row * TOPK + tid] = e / Z;
  }
}

// ---------------------------------------------------------------------------
// Kernel 3b: streaming dense-weights fill (register float4 zeros + scatter
// after barrier) + fused gather (fully unrolled: 32 independent loads in
// flight). One block per row, ~0.4 KB LDS -> 8 blocks/CU.
// ---------------------------------------------------------------------------
__global__ __launch_bounds__(256) void fill_gather_kernel(
    const int* __restrict__ selC, const float* __restrict__ selWt,
    float* __restrict__ weights, const float* __restrict__ v,
    float* __restrict__ fused, unsigned short* __restrict__ fb) {
  __shared__ int sc[TOPK];
  __shared__ float sw[TOPK];
  int tid = threadIdx.x;
  int row = blockIdx.x;
  if (tid < TOPK) {
    sc[tid] = selC[(size_t)row * TOPK + tid];
    sw[tid] = selWt[(size_t)row * TOPK + tid];
  }

  // zero the dense row straight from registers (overwrites the fp16 scores,
  // which topk_kernel has already consumed)
  float* wrow = weights + (size_t)row * NN;
  float4 z4 = {0.0f, 0.0f, 0.0f, 0.0f};
#pragma unroll
  for (int c = 0; c < 8; c++) *(float4*)(wrow + c * 1024 + tid * 4) = z4;
  __syncthreads();   // zeros drained (vmcnt(0) before barrier) + sc/sw visible
  if (tid < TOPK) wrow[sc[tid]] = sw[tid];

  // fused[row][tid] = sum_i w_i * v[col_i][tid]; full unroll -> loads overlap
  float acc = 0.0f;
#pragma unroll
  for (int i = 0; i < TOPK; i++)
    acc += sw[i] * v[(size_t)sc[i] * DD + tid];
  fused[(size_t)row * DD + tid] = acc;
  fb[(size_t)row * DD + tid] = f2bf(acc);
}

// ---------------------------------------------------------------------------
// Kernel 4: gate = sigmoid([x|fused] @ Wg.T + bg); out = g*x + (1-g)*fused.
// bf16 MFMA, K=512 (xb then fb). grid (16, 64): 16-col strip x 128 rows
// (finer x-split for 4 blocks/CU occupancy).
// ---------------------------------------------------------------------------
__global__ __launch_bounds__(256) void gate_kernel(
    const unsigned short* __restrict__ xb, const unsigned short* __restrict__ fb,
    const unsigned short* __restrict__ wgb, const float* __restrict__ bg,
    const float* __restrict__ x, const float* __restrict__ fused,
    float* __restrict__ out) {
  int tid = threadIdx.x;
  int w = tid >> 6, lane = tid & 63;
  int quad = lane >> 4, l16 = lane & 15;
  int rb = blockIdx.y * 128;
  int cs = blockIdx.x * 16;

  floatx4 acc[2];
  acc[0] = (floatx4){0.f, 0.f, 0.f, 0.f};
  acc[1] = (floatx4){0.f, 0.f, 0.f, 0.f};

#pragma unroll 1
  for (int kc = 0; kc < 2; kc++) {
    const unsigned short* asrc = kc ? fb : xb;
    short8v afrag[2][8];
#pragma unroll
    for (int rh = 0; rh < 2; rh++)
#pragma unroll
      for (int kbi = 0; kbi < 8; kbi++) {
        int row = rb + w * 32 + rh * 16 + l16;
        afrag[rh][kbi] =
            *(const short8v*)(asrc + (size_t)row * 256 + kbi * 32 + quad * 8);
      }
#pragma unroll
    for (int kbi = 0; kbi < 8; kbi++) {
      int col = cs + l16;
      short8v b = *(const short8v*)(wgb + (size_t)col * 512 + kc * 256 + kbi * 32 + quad * 8);
      acc[0] = __builtin_amdgcn_mfma_f32_16x16x32_bf16(afrag[0][kbi], b, acc[0], 0, 0, 0);
      acc[1] = __builtin_amdgcn_mfma_f32_16x16x32_bf16(afrag[1][kbi], b, acc[1], 0, 0, 0);
    }
  }
#pragma unroll
  for (int rh = 0; rh < 2; rh++)
#pragma unroll
    for (int r = 0; r < 4; r++) {
      int row = rb + w * 32 + rh * 16 + quad * 4 + r;
      int col = cs + l16;
      float t = acc[rh][r] + bg[col];
      float g = 1.0f / (1.0f + __expf(-t));
      size_t o = (size_t)row * 256 + col;
      out[o] = g * x[o] + (1.0f - g) * fused[o];
    }
}

// ---------------------------------------------------------------------------
extern "C" void kernel_launch(void* const* d_in, const int* in_sizes, int n_in,
                              void* d_out, int out_size, void* d_ws, size_t ws_size,
                              hipStream_t stream) {
  const float* x      = (const float*)d_in[0];
  const float* causal = (const float*)d_in[2];
  const float* Wq = (const float*)d_in[3];
  const float* bq = (const float*)d_in[4];
  const float* Wk = (const float*)d_in[5];
  const float* bk = (const float*)d_in[6];
  const float* Wv = (const float*)d_in[7];
  const float* bv = (const float*)d_in[8];
  const float* Wg = (const float*)d_in[9];
  const float* bg = (const float*)d_in[10];

  float* out = (float*)d_out;
  float* weights = out + (size_t)NN * DD;  // fp16 score scratch lives in row head

  char* ws = (char*)d_ws;
  unsigned short* xb    = (unsigned short*)(ws);                    // 4 MB
  unsigned short* wqkvb = (unsigned short*)(ws + (4u << 20));       // 384 KB
  unsigned short* wgb   = (unsigned short*)(ws + (4u << 20) + (512u << 10)); // 256 KB
  unsigned short* qb    = (unsigned short*)(ws + (5u << 20));       // 4 MB
  unsigned short* kb    = (unsigned short*)(ws + (9u << 20));       // 4 MB
  float* v     = (float*)(ws + (13u << 20));                        // 8 MB
  float* fused = (float*)(ws + (21u << 20));                        // 8 MB
  unsigned short* fb = (unsigned short*)(ws + (29u << 20));         // 4 MB
  // q/k are dead after score_kernel -> reuse their space for compact top-k
  int*   selC  = (int*)(ws + (5u << 20));                           // 1 MB
  float* selWt = (float*)(ws + (9u << 20));                         // 1 MB

  conv_kernel<<<dim3(2368), 256, 0, stream>>>(x, Wq, Wk, Wv, Wg, xb, wqkvb, wgb);
  qkv_kernel<<<dim3(6, 64, 4), 256, 0, stream>>>(xb, wqkvb, bq, bk, bv, qb, kb, v);
  score_kernel<<<dim3(SSTRIP, 64), 256, 0, stream>>>(qb, kb, causal, weights);
  topk_kernel<<<dim3(NN), 256, 0, stream>>>(weights, selC, selWt);
  fill_gather_kernel<<<dim3(NN), 256, 0, stream>>>(selC, selWt, weights, v, fused, fb);
  gate_kernel<<<dim3(16, 64), 256, 0, stream>>>(xb, fb, wgb, bg, x, fused, out);
}

// Round 5
// 873.780 us; speedup vs baseline: 1.0449x; 1.0449x over previous
//
#include <hip/hip_runtime.h>

#define NN 8192
#define DD 256
#define TOPK 32
#define SSTRIP 32   // score kernel: column strips
#define SW 256      // cols per strip

typedef __attribute__((ext_vector_type(8))) short short8v;
typedef __attribute__((ext_vector_type(4))) float floatx4;

__device__ __forceinline__ unsigned short f2bf(float f) {
  union { float f; unsigned int u; } x;
  x.f = f;
  unsigned int r = x.u + 0x7FFFu + ((x.u >> 16) & 1u);
  return (unsigned short)(r >> 16);
}
__device__ __forceinline__ unsigned short f2h(float f) {
  _Float16 h = (_Float16)f;
  return __builtin_bit_cast(unsigned short, h);
}
__device__ __forceinline__ float h2f(unsigned short u) {
  return (float)__builtin_bit_cast(_Float16, u);
}
// monotone 16-bit key for fp16: a<b (fp16) <=> key(a)<key(b) (uint16)
__device__ __forceinline__ unsigned int hkey(unsigned int u) {
  return (u & 0x8000u) ? ((~u) & 0xFFFFu) : (u | 0x8000u);
}
// Fragment-contiguous tile layout for MFMA operands (qb/kb):
// 16-row x 256-k panel stored as [kbi][l16][quad][8 elems] (4096 shorts).
// A wave's fragment load (l16, quad varying) is then 1KB CONTIGUOUS.
__device__ __forceinline__ size_t tile_off(int row, int j) {
  return ((size_t)(row >> 4) * 4096) + (size_t)(((j >> 5) * 512) +
         ((row & 15) * 32) + (((j >> 3) & 3) * 8) + (j & 7));
}

// ---------------------------------------------------------------------------
// Kernel 0: bf16 conversions. xb = bf16(x); wqkvb = bf16([Wq;Wk;Wv]);
// wgb = bf16(Wg). One float4 group per thread.
// ---------------------------------------------------------------------------
__global__ __launch_bounds__(256) void conv_kernel(
    const float* __restrict__ x,
    const float* __restrict__ Wq, const float* __restrict__ Wk,
    const float* __restrict__ Wv, const float* __restrict__ Wg,
    unsigned short* __restrict__ xb, unsigned short* __restrict__ wqkvb,
    unsigned short* __restrict__ wgb) {
  int g = blockIdx.x * 256 + threadIdx.x;   // float4 group id
  const float* src;
  unsigned short* dst;
  int e;
  if (g < 524288) {                 // x: 2097152 elems
    e = g * 4; src = x + e; dst = xb + e;
  } else if (g < 524288 + 49152) {  // Wq|Wk|Wv: 3 x 65536
    int e2 = (g - 524288) * 4;
    int which = e2 >> 16;
    int off = e2 & 65535;
    src = ((which == 0) ? Wq : (which == 1) ? Wk : Wv) + off;
    dst = wqkvb + which * 65536 + off;
  } else {                          // Wg: 131072
    int e3 = (g - 524288 - 49152) * 4;
    src = Wg + e3; dst = wgb + e3;
  }
  float4 f4 = *(const float4*)src;
  dst[0] = f2bf(f4.x); dst[1] = f2bf(f4.y);
  dst[2] = f2bf(f4.z); dst[3] = f2bf(f4.w);
}

// ---------------------------------------------------------------------------
// Kernel 1: q,k,v = x @ W.T + b via bf16 MFMA. q scaled by 1/16 (folded for
// scores). grid (6, 64, 4). q/k stored in fragment-contiguous tile layout.
// ---------------------------------------------------------------------------
__global__ __launch_bounds__(256) void qkv_kernel(
    const unsigned short* __restrict__ xb,
    const unsigned short* __restrict__ wqkvb,
    const float* __restrict__ bq, const float* __restrict__ bk,
    const float* __restrict__ bvb,
    unsigned short* __restrict__ qb, unsigned short* __restrict__ kb,
    float* __restrict__ v) {
  int tid = threadIdx.x;
  int w = tid >> 6, lane = tid & 63;
  int quad = lane >> 4, l16 = lane & 15;
  int rb = blockIdx.y * 128;
  int cs = blockIdx.x * 128;   // 0..767 in steps of 128 (never crosses 256-bnd)
  int cb = cs + blockIdx.z * 32;

  short8v afrag[2][8];
#pragma unroll
  for (int rh = 0; rh < 2; rh++)
#pragma unroll
    for (int kbi = 0; kbi < 8; kbi++) {
      int row = rb + w * 32 + rh * 16 + l16;
      afrag[rh][kbi] =
          *(const short8v*)(xb + (size_t)row * 256 + kbi * 32 + quad * 8);
    }

  floatx4 zero4 = {0.0f, 0.0f, 0.0f, 0.0f};
  floatx4 acc[2][2];
  acc[0][0] = zero4; acc[0][1] = zero4; acc[1][0] = zero4; acc[1][1] = zero4;
#pragma unroll
  for (int kbi = 0; kbi < 8; kbi++) {
    short8v b0 = *(const short8v*)(wqkvb + (size_t)(cb + l16) * 256 + kbi * 32 + quad * 8);
    short8v b1 = *(const short8v*)(wqkvb + (size_t)(cb + 16 + l16) * 256 + kbi * 32 + quad * 8);
    acc[0][0] = __builtin_amdgcn_mfma_f32_16x16x32_bf16(afrag[0][kbi], b0, acc[0][0], 0, 0, 0);
    acc[0][1] = __builtin_amdgcn_mfma_f32_16x16x32_bf16(afrag[0][kbi], b1, acc[0][1], 0, 0, 0);
    acc[1][0] = __builtin_amdgcn_mfma_f32_16x16x32_bf16(afrag[1][kbi], b0, acc[1][0], 0, 0, 0);
    acc[1][1] = __builtin_amdgcn_mfma_f32_16x16x32_bf16(afrag[1][kbi], b1, acc[1][1], 0, 0, 0);
  }
#pragma unroll
  for (int rh = 0; rh < 2; rh++)
#pragma unroll
    for (int ch = 0; ch < 2; ch++)
#pragma unroll
      for (int r = 0; r < 4; r++) {
        int row = rb + w * 32 + rh * 16 + quad * 4 + r;
        int col = cb + ch * 16 + l16;           // 0..767
        int which = col >> 8;
        int j = col & 255;
        const float* bias = (which == 0) ? bq : (which == 1) ? bk : bvb;
        float val = acc[rh][ch][r] + bias[j];
        if (which == 0)      qb[tile_off(row, j)] = f2bf(val * 0.0625f);  // /16 folds 1/sqrt(d)
        else if (which == 1) kb[tile_off(row, j)] = f2bf(val);
        else                 v[(size_t)row * 256 + j] = val;
      }
}

// ---------------------------------------------------------------------------
// Kernel 2: biased scores s = q@k^T (q pre-scaled) + log(clip(causal,1e-6)),
// stored fp16 INSIDE the weights buffer (first 16KB of each 32KB row).
// Stored position within 32-col group: p = l16*2 + ch  (col = ch*16 + l16).
// grid (SSTRIP, 64). q/k read from fragment-contiguous tiles (1KB/instr);
// causal loads hoisted above the MFMA loop to hide HBM latency.
// ---------------------------------------------------------------------------
__global__ __launch_bounds__(256) void score_kernel(
    const unsigned short* __restrict__ qb,
    const unsigned short* __restrict__ kb,
    const float* __restrict__ causal,
    float* __restrict__ weights) {
  int tid = threadIdx.x;
  int w = tid >> 6, lane = tid & 63;
  int quad = lane >> 4, l16 = lane & 15;
  int rb = blockIdx.y * 128;
  int cs = blockIdx.x * SW;
  int fragoff = l16 * 32 + quad * 8;   // lane offset within 1KB fragment slice

  short8v afrag[2][8];
#pragma unroll
  for (int rh = 0; rh < 2; rh++) {
    int gA = (rb + w * 32 + rh * 16) >> 4;   // row-group (rows are 16-aligned)
#pragma unroll
    for (int kbi = 0; kbi < 8; kbi++)
      afrag[rh][kbi] =
          *(const short8v*)(qb + (size_t)gA * 4096 + kbi * 512 + fragoff);
  }

  floatx4 zero4 = {0.0f, 0.0f, 0.0f, 0.0f};
  for (int it = 0; it < SW / 32; it++) {
    int cb = cs + it * 32;

    // prefetch causal values for this 32-col group (16 HBM loads in flight
    // across the whole MFMA phase)
    float cpre[2][4][2];
#pragma unroll
    for (int rh = 0; rh < 2; rh++)
#pragma unroll
      for (int r = 0; r < 4; r++) {
        int grow = rb + w * 32 + rh * 16 + quad * 4 + r;
        cpre[rh][r][0] = causal[(size_t)grow * NN + cb + l16];
        cpre[rh][r][1] = causal[(size_t)grow * NN + cb + 16 + l16];
      }

    const unsigned short* kbase = kb + (size_t)(cb >> 4) * 4096 + fragoff;
    floatx4 acc[2][2];
    acc[0][0] = zero4; acc[0][1] = zero4; acc[1][0] = zero4; acc[1][1] = zero4;
#pragma unroll
    for (int kbi = 0; kbi < 8; kbi++) {
      short8v b0 = *(const short8v*)(kbase + kbi * 512);          // cols cb..cb+15
      short8v b1 = *(const short8v*)(kbase + 4096 + kbi * 512);   // cols cb+16..cb+31
      acc[0][0] = __builtin_amdgcn_mfma_f32_16x16x32_bf16(afrag[0][kbi], b0, acc[0][0], 0, 0, 0);
      acc[0][1] = __builtin_amdgcn_mfma_f32_16x16x32_bf16(afrag[0][kbi], b1, acc[0][1], 0, 0, 0);
      acc[1][0] = __builtin_amdgcn_mfma_f32_16x16x32_bf16(afrag[1][kbi], b0, acc[1][0], 0, 0, 0);
      acc[1][1] = __builtin_amdgcn_mfma_f32_16x16x32_bf16(afrag[1][kbi], b1, acc[1][1], 0, 0, 0);
    }
#pragma unroll
    for (int rh = 0; rh < 2; rh++)
#pragma unroll
      for (int r = 0; r < 4; r++) {
        int grow = rb + w * 32 + rh * 16 + quad * 4 + r;
        float s0 = acc[rh][0][r] + __logf(fmaxf(cpre[rh][r][0], 1e-6f));
        float s1 = acc[rh][1][r] + __logf(fmaxf(cpre[rh][r][1], 1e-6f));
        unsigned int pk = (unsigned int)f2h(s0) | ((unsigned int)f2h(s1) << 16);
        unsigned short* sbrow = (unsigned short*)(weights + (size_t)grow * NN);
        *(unsigned int*)(sbrow + cb + l16 * 2) = pk;
      }
  }
}

// ---------------------------------------------------------------------------
// Kernel 3a: per-row top-32 via register binary-search on fp16 keys + softmax.
// Writes COMPACT selC[row*32+i] / selWt[row*32+i] only. One block per row.
// Thread owns stored positions {c*2048 + tid*8 + e : c<4, e<8}.
// ---------------------------------------------------------------------------
__global__ __launch_bounds__(256) void topk_kernel(
    const float* __restrict__ weights,
    int* __restrict__ selC, float* __restrict__ selWt) {
  __shared__ int part[72];        // binary-search partials (17 x 4)
  __shared__ int part2[8];        // scan partials
  __shared__ int selCol[TOPK];
  __shared__ float selSc[TOPK];

  int tid = threadIdx.x;
  int w = tid >> 6, lane = tid & 63;
  int row = blockIdx.x;
  const unsigned short* sb = (const unsigned short*)(weights + (size_t)row * NN);

  // load 32 fp16 scores (coalesced), build packed monotone keys
  uint4 raw[4];
#pragma unroll
  for (int c = 0; c < 4; c++)
    raw[c] = *(const uint4*)(sb + c * 2048 + tid * 8);
  unsigned int keys[16];
#pragma unroll
  for (int c = 0; c < 4; c++) {
    unsigned int rr[4] = {raw[c].x, raw[c].y, raw[c].z, raw[c].w};
#pragma unroll
    for (int u = 0; u < 4; u++) {
      unsigned int klo = hkey(rr[u] & 0xFFFFu);
      unsigned int khi = hkey(rr[u] >> 16);
      keys[c * 4 + u] = klo | (khi << 16);
    }
  }

  // binary search: smallest t with count(key > t) < TOPK  -> t = 32nd key
  int lo = 0, hi = 65535;
#pragma unroll 1
  for (int it = 0; it < 16; it++) {
    unsigned int mid = (unsigned int)((lo + hi) >> 1);
    int cnt = 0;
#pragma unroll
    for (int u = 0; u < 16; u++) {
      cnt += ((keys[u] & 0xFFFFu) > mid);
      cnt += ((keys[u] >> 16) > mid);
    }
#pragma unroll
    for (int off = 32; off >= 1; off >>= 1) cnt += __shfl_xor(cnt, off, 64);
    if (lane == 0) part[it * 4 + w] = cnt;
    __syncthreads();
    int tot = part[it * 4] + part[it * 4 + 1] + part[it * 4 + 2] + part[it * 4 + 3];
    if (lo < hi) { if (tot < TOPK) hi = (int)mid; else lo = (int)mid + 1; }
  }
  unsigned int K = (unsigned int)lo;

  // nGt = count(key > K)
  {
    int cnt = 0;
#pragma unroll
    for (int u = 0; u < 16; u++) {
      cnt += ((keys[u] & 0xFFFFu) > K);
      cnt += ((keys[u] >> 16) > K);
    }
#pragma unroll
    for (int off = 32; off >= 1; off >>= 1) cnt += __shfl_xor(cnt, off, 64);
    if (lane == 0) part[64 + w] = cnt;
  }
  __syncthreads();
  int nGt = part[64] + part[65] + part[66] + part[67];

  // per-thread counts + shuffle-based prefix scans for deterministic slots
  int cGt = 0, cEq = 0;
#pragma unroll
  for (int u = 0; u < 16; u++) {
    unsigned int a = keys[u] & 0xFFFFu, b = keys[u] >> 16;
    cGt += (a > K) + (b > K);
    cEq += (a == K) + (b == K);
  }
  int sGt = cGt;
#pragma unroll
  for (int off = 1; off < 64; off <<= 1) {
    int t = __shfl_up(sGt, off, 64);
    if (lane >= off) sGt += t;
  }
  if (lane == 63) part2[w] = sGt;
  int sEq = cEq;
#pragma unroll
  for (int off = 1; off < 64; off <<= 1) {
    int t = __shfl_up(sEq, off, 64);
    if (lane >= off) sEq += t;
  }
  if (lane == 63) part2[4 + w] = sEq;
  __syncthreads();
  int offGt = 0, offEq = 0;
  for (int j = 0; j < w; j++) { offGt += part2[j]; offEq += part2[4 + j]; }
  int posG = offGt + sGt - cGt;          // exclusive prefix of cGt
  int posT = nGt + offEq + sEq - cEq;    // tie slots after all strict-greater

  // collect selected entries (fixed order -> deterministic)
#pragma unroll
  for (int c = 0; c < 4; c++) {
    unsigned int rr[4] = {raw[c].x, raw[c].y, raw[c].z, raw[c].w};
#pragma unroll
    for (int e = 0; e < 8; e++) {
      unsigned int u16 = (e & 1) ? (rr[e >> 1] >> 16) : (rr[e >> 1] & 0xFFFFu);
      unsigned int k = hkey(u16);
      if (k > K || (k == K && posT < TOPK)) {
        int p = c * 2048 + tid * 8 + e;            // stored position
        int g = p >> 5, wi = p & 31;
        int col = (g << 5) + ((wi & 1) << 4) + (wi >> 1);  // invert store perm
        int slot = (k > K) ? posG : posT;
        selCol[slot] = col;
        selSc[slot] = h2f((unsigned short)u16);
      }
      if (k > K) posG++;
      else if (k == K) posT++;
    }
  }
  __syncthreads();

  // softmax over the 32 selected (wave-parallel, deterministic), compact out
  if (tid < TOPK) {
    float s = selSc[tid];
    float m = s;
#pragma unroll
    for (int off = 16; off >= 1; off >>= 1) m = fmaxf(m, __shfl_xor(m, off, 64));
    float e = __expf(s - m);
    float Z = e;
#pragma unroll
    for (int off = 16; off >= 1; off >>= 1) Z += __shfl_xor(Z, off, 64);
    selC[(size_t)row * TOPK + tid] = selCol[tid];
    selWt[(size_t)row * TOPK + tid] = e / Z;
  }
}

// ---------------------------------------------------------------------------
// Kernel 3b: streaming dense-weights fill (register float4 zeros + scatter
// after barrier) + fused gather (fully unrolled: 32 independent loads in
// flight). One block per row, ~0.4 KB LDS -> 8 blocks/CU.
// ---------------------------------------------------------------------------
__global__ __launch_bounds__(256) void fill_gather_kernel(
    const int* __restrict__ selC, const float* __restrict__ selWt,
    float* __restrict__ weights, const float* __restrict__ v,
    float* __restrict__ fused, unsigned short* __restrict__ fb) {
  __shared__ int sc[TOPK];
  __shared__ float sw[TOPK];
  int tid = threadIdx.x;
  int row = blockIdx.x;
  if (tid < TOPK) {
    sc[tid] = selC[(size_t)row * TOPK + tid];
    sw[tid] = selWt[(size_t)row * TOPK + tid];
  }

  // zero the dense row straight from registers (overwrites the fp16 scores,
  // which topk_kernel has already consumed)
  float* wrow = weights + (size_t)row * NN;
  float4 z4 = {0.0f, 0.0f, 0.0f, 0.0f};
#pragma unroll
  for (int c = 0; c < 8; c++) *(float4*)(wrow + c * 1024 + tid * 4) = z4;
  __syncthreads();   // zeros drained (vmcnt(0) before barrier) + sc/sw visible
  if (tid < TOPK) wrow[sc[tid]] = sw[tid];

  // fused[row][tid] = sum_i w_i * v[col_i][tid]; full unroll -> loads overlap
  float acc = 0.0f;
#pragma unroll
  for (int i = 0; i < TOPK; i++)
    acc += sw[i] * v[(size_t)sc[i] * DD + tid];
  fused[(size_t)row * DD + tid] = acc;
  fb[(size_t)row * DD + tid] = f2bf(acc);
}

// ---------------------------------------------------------------------------
// Kernel 4: gate = sigmoid([x|fused] @ Wg.T + bg); out = g*x + (1-g)*fused.
// bf16 MFMA, K=512 (xb then fb). grid (16, 64).
// ---------------------------------------------------------------------------
__global__ __launch_bounds__(256) void gate_kernel(
    const unsigned short* __restrict__ xb, const unsigned short* __restrict__ fb,
    const unsigned short* __restrict__ wgb, const float* __restrict__ bg,
    const float* __restrict__ x, const float* __restrict__ fused,
    float* __restrict__ out) {
  int tid = threadIdx.x;
  int w = tid >> 6, lane = tid & 63;
  int quad = lane >> 4, l16 = lane & 15;
  int rb = blockIdx.y * 128;
  int cs = blockIdx.x * 16;

  floatx4 acc[2];
  acc[0] = (floatx4){0.f, 0.f, 0.f, 0.f};
  acc[1] = (floatx4){0.f, 0.f, 0.f, 0.f};

#pragma unroll 1
  for (int kc = 0; kc < 2; kc++) {
    const unsigned short* asrc = kc ? fb : xb;
    short8v afrag[2][8];
#pragma unroll
    for (int rh = 0; rh < 2; rh++)
#pragma unroll
      for (int kbi = 0; kbi < 8; kbi++) {
        int row = rb + w * 32 + rh * 16 + l16;
        afrag[rh][kbi] =
            *(const short8v*)(asrc + (size_t)row * 256 + kbi * 32 + quad * 8);
      }
#pragma unroll
    for (int kbi = 0; kbi < 8; kbi++) {
      int col = cs + l16;
      short8v b = *(const short8v*)(wgb + (size_t)col * 512 + kc * 256 + kbi * 32 + quad * 8);
      acc[0] = __builtin_amdgcn_mfma_f32_16x16x32_bf16(afrag[0][kbi], b, acc[0], 0, 0, 0);
      acc[1] = __builtin_amdgcn_mfma_f32_16x16x32_bf16(afrag[1][kbi], b, acc[1], 0, 0, 0);
    }
  }
#pragma unroll
  for (int rh = 0; rh < 2; rh++)
#pragma unroll
    for (int r = 0; r < 4; r++) {
      int row = rb + w * 32 + rh * 16 + quad * 4 + r;
      int col = cs + l16;
      float t = acc[rh][r] + bg[col];
      float g = 1.0f / (1.0f + __expf(-t));
      size_t o = (size_t)row * 256 + col;
      out[o] = g * x[o] + (1.0f - g) * fused[o];
    }
}

// ---------------------------------------------------------------------------
extern "C" void kernel_launch(void* const* d_in, const int* in_sizes, int n_in,
                              void* d_out, int out_size, void* d_ws, size_t ws_size,
                              hipStream_t stream) {
  const float* x      = (const float*)d_in[0];
  const float* causal = (const float*)d_in[2];
  const float* Wq = (const float*)d_in[3];
  const float* bq = (const float*)d_in[4];
  const float* Wk = (const float*)d_in[5];
  const float* bk = (const float*)d_in[6];
  const float* Wv = (const float*)d_in[7];
  const float* bv = (const float*)d_in[8];
  const float* Wg = (const float*)d_in[9];
  const float* bg = (const float*)d_in[10];

  float* out = (float*)d_out;
  float* weights = out + (size_t)NN * DD;  // fp16 score scratch lives in row head

  char* ws = (char*)d_ws;
  unsigned short* xb    = (unsigned short*)(ws);                    // 4 MB
  unsigned short* wqkvb = (unsigned short*)(ws + (4u << 20));       // 384 KB
  unsigned short* wgb   = (unsigned short*)(ws + (4u << 20) + (512u << 10)); // 256 KB
  unsigned short* qb    = (unsigned short*)(ws + (5u << 20));       // 4 MB (tiled)
  unsigned short* kb    = (unsigned short*)(ws + (9u << 20));       // 4 MB (tiled)
  float* v     = (float*)(ws + (13u << 20));                        // 8 MB
  float* fused = (float*)(ws + (21u << 20));                        // 8 MB
  unsigned short* fb = (unsigned short*)(ws + (29u << 20));         // 4 MB
  // q/k are dead after score_kernel -> reuse their space for compact top-k
  int*   selC  = (int*)(ws + (5u << 20));                           // 1 MB
  float* selWt = (float*)(ws + (9u << 20));                         // 1 MB

  conv_kernel<<<dim3(2368), 256, 0, stream>>>(x, Wq, Wk, Wv, Wg, xb, wqkvb, wgb);
  qkv_kernel<<<dim3(6, 64, 4), 256, 0, stream>>>(xb, wqkvb, bq, bk, bv, qb, kb, v);
  score_kernel<<<dim3(SSTRIP, 64), 256, 0, stream>>>(qb, kb, causal, weights);
  topk_kernel<<<dim3(NN), 256, 0, stream>>>(weights, selC, selWt);
  fill_gather_kernel<<<dim3(NN), 256, 0, stream>>>(selC, selWt, weights, v, fused, fb);
  gate_kernel<<<dim3(16, 64), 256, 0, stream>>>(xb, fb, wgb, bg, x, fused, out);
}